// Round 1
// baseline (591.586 us; speedup 1.0000x reference)
//
#include <hip/hip_runtime.h>

// Problem constants (from reference)
#define BB 4
#define SS 131072           // 2^17
#define DD 64
#define NV 6890
#define NPTS (BB * SS)      // 524288 points

__global__ __launch_bounds__(256) void feat_dict_kernel(
    const float* __restrict__ coords,     // [B,S,3]
    const int*   __restrict__ idx,        // [B]
    const int*   __restrict__ smpl_F,     // [F,3]
    const int*   __restrict__ fid,        // [B,S]
    const float* __restrict__ weights,    // [B,S,3]
    const float* __restrict__ sdf,        // [B,S,1]
    const float* __restrict__ hitpt,      // [B,S,3]
    const float* __restrict__ codebooks,  // [NS,NV,D]
    float* __restrict__ out_wf,           // [B,S,D]
    float* __restrict__ out_cf,           // [B,S,3]
    float* __restrict__ out_nm)           // [B,S,3]
{
    int gid = blockIdx.x * blockDim.x + threadIdx.x;
    int p   = gid >> 4;          // point index
    int dq  = (gid & 15) << 2;   // float4 offset within D=64 row
    if (p >= NPTS) return;

    int b    = p >> 17;          // S = 2^17
    int f    = fid[p];
    int subj = idx[b];

    int v0 = smpl_F[3 * f + 0];
    int v1 = smpl_F[3 * f + 1];
    int v2 = smpl_F[3 * f + 2];

    float w0 = weights[3 * p + 0];
    float w1 = weights[3 * p + 1];
    float w2 = weights[3 * p + 2];

    const float* cb = codebooks + (size_t)subj * (size_t)(NV * DD);
    const float4 a0 = *(const float4*)(cb + (size_t)v0 * DD + dq);
    const float4 a1 = *(const float4*)(cb + (size_t)v1 * DD + dq);
    const float4 a2 = *(const float4*)(cb + (size_t)v2 * DD + dq);

    float4 r;
    r.x = a0.x * w0 + a1.x * w1 + a2.x * w2;
    r.y = a0.y * w0 + a1.y * w1 + a2.y * w2;
    r.z = a0.z * w0 + a1.z * w1 + a2.z * w2;
    r.w = a0.w * w0 + a1.w * w1 + a2.w * w2;
    *(float4*)(out_wf + (size_t)p * DD + dq) = r;

    // Lane 0 of each 16-lane group handles normal + coords_feats for its point.
    if ((gid & 15) == 0) {
        float cx = coords[3 * p + 0], cy = coords[3 * p + 1], cz = coords[3 * p + 2];
        float hx = hitpt[3 * p + 0],  hy = hitpt[3 * p + 1],  hz = hitpt[3 * p + 2];
        float dx = hx - cx, dy = hy - cy, dz = hz - cz;
        float n   = sqrtf(dx * dx + dy * dy + dz * dz);
        float inv = 1.0f / fmaxf(n, 1e-6f);
        out_nm[3 * p + 0] = dx * inv;
        out_nm[3 * p + 1] = dy * inv;
        out_nm[3 * p + 2] = dz * inv;
        // coords_feats = [weights[1], weights[2], sdf]
        out_cf[3 * p + 0] = w1;
        out_cf[3 * p + 1] = w2;
        out_cf[3 * p + 2] = sdf[p];
    }
}

extern "C" void kernel_launch(void* const* d_in, const int* in_sizes, int n_in,
                              void* d_out, int out_size, void* d_ws, size_t ws_size,
                              hipStream_t stream) {
    const float* coords    = (const float*)d_in[0];
    const int*   idx       = (const int*)d_in[1];
    const int*   smpl_F    = (const int*)d_in[2];
    const int*   fid       = (const int*)d_in[3];
    const float* weights   = (const float*)d_in[4];
    const float* sdf       = (const float*)d_in[5];
    const float* hitpt     = (const float*)d_in[6];
    const float* codebooks = (const float*)d_in[7];

    float* out_wf = (float*)d_out;                       // [B,S,D]
    float* out_cf = out_wf + (size_t)NPTS * DD;          // [B,S,3]
    float* out_nm = out_cf + (size_t)NPTS * 3;           // [B,S,3]

    const int threads = 256;
    const long long total = (long long)NPTS * 16;
    const int blocks = (int)((total + threads - 1) / threads);

    feat_dict_kernel<<<blocks, threads, 0, stream>>>(
        coords, idx, smpl_F, fid, weights, sdf, hitpt, codebooks,
        out_wf, out_cf, out_nm);
}